// Round 13
// baseline (57.250 us; speedup 1.0000x reference)
//
#include <hip/hip_runtime.h>

// R13 = ABLATION ROUND. Two dispatches in the graph:
//   V1 (-> d_ws): R12's exact structure with the 32-instr tail replaced by
//       a single `acc += d[0]` (MFMA+ds_read+loop kept live through real
//       dataflow), main loop repeated REPS=4 times. Isolates the
//       {staging + ds_read + MFMA + loop-overhead} core cost:
//       dur_us ~= 34 + 4*T_core.
//   FINAL (-> d_out): bit-identical to R12 (passing, absmax 0.5) for
//       correctness and baseline continuity.
// Everything else (encoding, grid, LDS, reduce) identical to R12.

#define NATOMS 4096
#define KTOT   2048
#define BLOCK  1024
#define ATILES 128
#define TPW    64
#define REPS   4

typedef float  f32x16 __attribute__((ext_vector_type(16)));
typedef __bf16 bf16x8 __attribute__((ext_vector_type(8)));

__device__ __forceinline__ void stage_atoms(const float* __restrict__ Cb,
                                            bf16x8* __restrict__ sA, int tid) {
    constexpr float S2 = 9.064720283654388f;
    const __bf16 one = (__bf16)1.0f;
    const __bf16 zb  = (__bf16)0.0f;
    for (int j = tid; j < NATOMS; j += BLOCK) {
        float x = Cb[3 * j + 0];
        float y = Cb[3 * j + 1];
        float z = Cb[3 * j + 2];
        __bf16 xh = (__bf16)x; __bf16 xl = (__bf16)(x - (float)xh);
        __bf16 yh = (__bf16)y; __bf16 yl = (__bf16)(y - (float)yh);
        __bf16 zh = (__bf16)z; __bf16 zl = (__bf16)(z - (float)zh);
        float wn = -S2 * (x * x + y * y + z * z);
        __bf16 wh = (__bf16)wn; __bf16 wl = (__bf16)(wn - (float)wh);
        const int t = j >> 5, r = j & 31;
        bf16x8 f0 = {xh, yh, zh, wh, one, xl, yl, zl};
        bf16x8 f1 = {wl, one, xh, yh, zh, zb, zb, zb};
        sA[t * 64 + r]      = f0;
        sA[t * 64 + 32 + r] = f1;
    }
}

__device__ __forceinline__ bf16x8 make_bfrag(const float* __restrict__ dom,
                                             int k, int lane) {
    constexpr float S2    = 9.064720283654388f;
    constexpr float S1    = 18.129440567308776f;
    constexpr float SCALE = 0.001953125f;   // 2^-9
    constexpr float BIAS  = 126.9437f;
    const __bf16 zb = (__bf16)0.0f;
    const float dx = dom[3 * k + 0], dy = dom[3 * k + 1], dz = dom[3 * k + 2];
    const float px = S1 * dx, py = S1 * dy, pz = S1 * dz;
    __bf16 pxh = (__bf16)px; __bf16 pxl = (__bf16)(px - (float)pxh);
    __bf16 pyh = (__bf16)py; __bf16 pyl = (__bf16)(py - (float)pyh);
    __bf16 pzh = (__bf16)pz; __bf16 pzl = (__bf16)(pz - (float)pzh);
    const float dkf = -S2 * (dx * dx + dy * dy + dz * dz) + BIAS;
    __bf16 dkh = (__bf16)dkf; __bf16 dkl = (__bf16)(dkf - (float)dkh);
    __bf16 pxh_s = (__bf16)((float)pxh * SCALE), pxl_s = (__bf16)((float)pxl * SCALE);
    __bf16 pyh_s = (__bf16)((float)pyh * SCALE), pyl_s = (__bf16)((float)pyl * SCALE);
    __bf16 pzh_s = (__bf16)((float)pzh * SCALE), pzl_s = (__bf16)((float)pzl * SCALE);
    __bf16 dkh_s = (__bf16)((float)dkh * SCALE), dkl_s = (__bf16)((float)dkl * SCALE);
    __bf16 sc9   = (__bf16)SCALE;
    if (lane < 32) {
        bf16x8 t0 = {pxh_s, pyh_s, pzh_s, sc9, dkh_s, pxh_s, pyh_s, pzh_s};
        return t0;
    } else {
        bf16x8 t1 = {sc9, dkl_s, pxl_s, pyl_s, pzl_s, zb, zb, zb};
        return t1;
    }
}

// ---------------- V1: core ablation (tail = 1 add), REPS x main loop -------
__global__ __launch_bounds__(BLOCK) void theta_ablate_core(
        const float* __restrict__ C, const float* __restrict__ dom,
        float* __restrict__ ws) {
    __shared__ bf16x8 sA[ATILES * 64];
    const int tid  = threadIdx.x;
    const int lane = tid & 63;
    const int w    = tid >> 6;
    const int b    = blockIdx.y;
    const int kg   = blockIdx.x;

    stage_atoms(C + (size_t)b * NATOMS * 3, sA, tid);
    const int kt = kg * 8 + (w & 7);
    const int k  = kt * 32 + (lane & 31);
    bf16x8 bfrag = make_bfrag(dom, k, lane);
    __syncthreads();

    const f32x16 zero = {};
    float acc = 0.f;
    const int t0i = (w >> 3) * TPW;
    for (int rep = 0; rep < REPS; ++rep) {
        #pragma unroll 2
        for (int t = t0i; t < t0i + TPW; ++t) {
            bf16x8 af = sA[t * 64 + lane];
            f32x16 d = __builtin_amdgcn_mfma_f32_32x32x16_bf16(af, bfrag, zero, 0, 0, 0);
            acc += d[0];   // keep the MFMA live; tail cost ~0
        }
    }
    float other = __shfl_xor(acc, 32, 64);
    float tot = acc + other;
    __syncthreads();
    float* red = (float*)sA;
    if (lane < 32) red[w * 32 + lane] = tot;
    __syncthreads();
    if (tid < 256) {
        const int t2 = tid >> 5;
        const int kc = tid & 31;
        float s = red[t2 * 32 + kc] + red[(t2 + 8) * 32 + kc];
        ws[(size_t)b * KTOT + (kg * 8 + t2) * 32 + kc] = s;
    }
}

// ---------------- FINAL: bit-identical to R12 (passing) --------------------
__global__ __launch_bounds__(BLOCK) void theta_layer_kernel(
        const float* __restrict__ C, const float* __restrict__ dom,
        float* __restrict__ out) {
    __shared__ bf16x8 sA[ATILES * 64];
    const int tid  = threadIdx.x;
    const int lane = tid & 63;
    const int w    = tid >> 6;
    const int b    = blockIdx.y;
    const int kg   = blockIdx.x;

    stage_atoms(C + (size_t)b * NATOMS * 3, sA, tid);
    const int kt = kg * 8 + (w & 7);
    const int k  = kt * 32 + (lane & 31);
    bf16x8 bfrag = make_bfrag(dom, k, lane);
    __syncthreads();

    const f32x16 zero = {};
    float a0 = 0.f, a1 = 0.f, a2 = 0.f, a3 = 0.f;
    const unsigned ONES = 0x3F803F80u;
    const int t0i = (w >> 3) * TPW;
    #pragma unroll 2
    for (int t = t0i; t < t0i + TPW; ++t) {
        bf16x8 af = sA[t * 64 + lane];
        f32x16 d = __builtin_amdgcn_mfma_f32_32x32x16_bf16(af, bfrag, zero, 0, 0, 0);
        float c0  = fmaxf(d[0],  0.0f), c1  = fmaxf(d[1],  0.0f);
        float c2  = fmaxf(d[2],  0.0f), c3  = fmaxf(d[3],  0.0f);
        float c4  = fmaxf(d[4],  0.0f), c5  = fmaxf(d[5],  0.0f);
        float c6  = fmaxf(d[6],  0.0f), c7  = fmaxf(d[7],  0.0f);
        float c8  = fmaxf(d[8],  0.0f), c9  = fmaxf(d[9],  0.0f);
        float c10 = fmaxf(d[10], 0.0f), c11 = fmaxf(d[11], 0.0f);
        float c12 = fmaxf(d[12], 0.0f), c13 = fmaxf(d[13], 0.0f);
        float c14 = fmaxf(d[14], 0.0f), c15 = fmaxf(d[15], 0.0f);
        unsigned p0, p1, p2, p3, p4, p5, p6, p7;
        asm("v_cvt_pknorm_u16_f32 %0, %1, %2" : "=v"(p0) : "v"(c0),  "v"(c1));
        asm("v_cvt_pknorm_u16_f32 %0, %1, %2" : "=v"(p1) : "v"(c2),  "v"(c3));
        asm("v_cvt_pknorm_u16_f32 %0, %1, %2" : "=v"(p2) : "v"(c4),  "v"(c5));
        asm("v_cvt_pknorm_u16_f32 %0, %1, %2" : "=v"(p3) : "v"(c6),  "v"(c7));
        asm("v_cvt_pknorm_u16_f32 %0, %1, %2" : "=v"(p4) : "v"(c8),  "v"(c9));
        asm("v_cvt_pknorm_u16_f32 %0, %1, %2" : "=v"(p5) : "v"(c10), "v"(c11));
        asm("v_cvt_pknorm_u16_f32 %0, %1, %2" : "=v"(p6) : "v"(c12), "v"(c13));
        asm("v_cvt_pknorm_u16_f32 %0, %1, %2" : "=v"(p7) : "v"(c14), "v"(c15));
        asm("v_dot2_f32_bf16 %0, %1, %2, %0" : "+v"(a0) : "v"(p0), "v"(ONES));
        asm("v_dot2_f32_bf16 %0, %1, %2, %0" : "+v"(a1) : "v"(p1), "v"(ONES));
        asm("v_dot2_f32_bf16 %0, %1, %2, %0" : "+v"(a2) : "v"(p2), "v"(ONES));
        asm("v_dot2_f32_bf16 %0, %1, %2, %0" : "+v"(a3) : "v"(p3), "v"(ONES));
        asm("v_dot2_f32_bf16 %0, %1, %2, %0" : "+v"(a0) : "v"(p4), "v"(ONES));
        asm("v_dot2_f32_bf16 %0, %1, %2, %0" : "+v"(a1) : "v"(p5), "v"(ONES));
        asm("v_dot2_f32_bf16 %0, %1, %2, %0" : "+v"(a2) : "v"(p6), "v"(ONES));
        asm("v_dot2_f32_bf16 %0, %1, %2, %0" : "+v"(a3) : "v"(p7), "v"(ONES));
    }
    float acc = (a0 + a1) + (a2 + a3);

    float other = __shfl_xor(acc, 32, 64);
    float tot = acc + other;
    __syncthreads();
    float* red = (float*)sA;
    if (lane < 32) red[w * 32 + lane] = tot;
    __syncthreads();
    if (tid < 256) {
        const int t2 = tid >> 5;
        const int kc = tid & 31;
        float s = red[t2 * 32 + kc] + red[(t2 + 8) * 32 + kc];
        out[(size_t)b * KTOT + (kg * 8 + t2) * 32 + kc] = s;
    }
}

extern "C" void kernel_launch(void* const* d_in, const int* in_sizes, int n_in,
                              void* d_out, int out_size, void* d_ws, size_t ws_size,
                              hipStream_t stream) {
    const float* C   = (const float*)d_in[0];
    const float* dom = (const float*)d_in[1];
    float* out       = (float*)d_out;
    float* ws        = (float*)d_ws;
    const int B = in_sizes[0] / (NATOMS * 3);  // 32
    dim3 grid(8, B);
    theta_ablate_core<<<grid, BLOCK, 0, stream>>>(C, dom, ws);
    theta_layer_kernel<<<grid, BLOCK, 0, stream>>>(C, dom, out);
}